// Round 12
// baseline (152.485 us; speedup 1.0000x reference)
//
#include <hip/hip_runtime.h>

#define NBINS   2048
#define NSLICE  16      // B*C = 4*4
#define BPSH    128     // blocks per slice (k_hist)
#define BLOCK   256
#define NV4     524288  // float4 per slice (2,097,152 / 4)
#define NCHUNK  16384   // 32-float4 chunks per slice (NV4/32)

static constexpr float kRange = 9.2104f;   // ce < -ln(1e-4) = 9.21034

// ws layout (bytes):
//  [0,64) tmax u32[16]; [64,128) pmax u32[16]; [128,192) losses f32[16]
//  [256, 256+131072) hist u32[NSLICE*NBINS]
#define WS_TMAX 0
#define WS_PMAX 64
#define WS_LOSS 128
#define WS_HIST 256
#define WS_USED (256 + NSLICE * NBINS * 4)

// ---- histogram over net+tgt with ONE wave-wide load per iteration:
//      lanes 0-31 stream tgt, lanes 32-63 stream the matching net float4s;
//      halves exchanged via shfl_xor(32). m13 shape: 1D grid-stride, plain
//      loads, no launch_bounds, no asm. Also computes tmax. ----
__global__ void k_hist(const float* __restrict__ net,
                       const float* __restrict__ tgt,
                       unsigned* __restrict__ hist,
                       unsigned* __restrict__ tmax)
{
    __shared__ unsigned lcnt[NBINS];            // 8 KB
    const int tid = threadIdx.x;
    for (int i = tid; i < NBINS; i += BLOCK) lcnt[i] = 0u;
    __syncthreads();

    const int slice = blockIdx.x >> 7;          // 128 blocks per slice
    const int lb    = blockIdx.x & 127;
    const int w     = tid >> 6;                 // wave 0..3
    const int l     = tid & 63;                 // lane
    const bool lo   = (l < 32);
    const float scale = (float)NBINS / kRange;

    const float4* t4 = (const float4*)tgt + (size_t)slice * NV4;
    const float4* p4 = (const float4*)net + (size_t)slice * NV4;
    const float4* base = lo ? t4 : p4;          // per-lane array select (once)
    const int lane31 = l & 31;

    float ltm = 0.f;
    // within-slice wave id 0..511; each iteration consumes one 32-float4
    // chunk of BOTH arrays (lower half tgt, upper half net)
    for (int c = lb * 4 + w; c < NCHUNK; c += BPSH * 4) {
        float4 v = base[(size_t)c * 32 + lane31];
        float4 o;                               // other half's data
        o.x = __shfl_xor(v.x, 32, 64);
        o.y = __shfl_xor(v.y, 32, 64);
        o.z = __shfl_xor(v.z, 32, 64);
        o.w = __shfl_xor(v.w, 32, 64);

        // lower lanes own elements 0,1 of the pair; upper lanes own 2,3.
        // For lower: t = v, p = o; for upper: t = o, p = v.
        float ta = lo ? v.x : o.z;
        float tb = lo ? v.y : o.w;
        float pa = lo ? o.x : v.z;
        float pb = lo ? o.y : v.w;

        float cea = -ta * __logf(pa);           // >= 0
        float ceb = -tb * __logf(pb);
        int ba = (int)(cea * scale);
        int bb = (int)(ceb * scale);
        ba = ba < 0 ? 0 : (ba > NBINS - 1 ? NBINS - 1 : ba);
        bb = bb < 0 ? 0 : (bb > NBINS - 1 ? NBINS - 1 : bb);
        atomicAdd(&lcnt[ba], 1u);               // ds_add_u32, no return
        atomicAdd(&lcnt[bb], 1u);
        ltm = fmaxf(ltm, fmaxf(ta, tb));        // owned t-elems partition data
    }
    __syncthreads();

    for (int i = tid; i < NBINS; i += BLOCK) {
        unsigned c = lcnt[i];
        if (c) atomicAdd(&hist[slice * NBINS + i], c);
    }

    for (int off = 32; off; off >>= 1)
        ltm = fmaxf(ltm, __shfl_down(ltm, off, 64));
    if ((tid & 63) == 0) atomicMax(&tmax[slice], __float_as_uint(ltm));
}

// ---- conditional pmax: reads mp only for slices with tmax == 0.
// active = !(tmax==0 && pmax==0): when tmax != 0, pmax is irrelevant.
// Deterministic: same inputs -> same tmax -> same branch.
__global__ void k_pmax_cond(const float* __restrict__ mp,
                            const unsigned* __restrict__ tmax,
                            unsigned* __restrict__ pmax)
{
    const int slice = blockIdx.x >> 7;       // 128 blocks per slice
    if (tmax[slice] != 0u) return;           // uniform branch, block retires

    const int tid = threadIdx.x;
    const int lb  = blockIdx.x & 127;
    const float4* m4 = (const float4*)mp + (size_t)slice * NV4;

    float lpm = 0.f;
    for (int i = lb * BLOCK + tid; i < NV4; i += 128 * BLOCK) {
        float4 m = m4[i];
        lpm = fmaxf(lpm, fmaxf(fmaxf(m.x, m.y), fmaxf(m.z, m.w)));
    }
    for (int off = 32; off; off >>= 1)
        lpm = fmaxf(lpm, __shfl_down(lpm, off, 64));
    if ((tid & 63) == 0) atomicMax(&pmax[slice], __float_as_uint(lpm));
}

// 16 blocks, one per slice: find threshold bin, top-k mean (bin centers).
__global__ __launch_bounds__(BLOCK) void k_select(
    const unsigned* __restrict__ hist, const unsigned* __restrict__ tmax,
    const unsigned* __restrict__ pmax, float* __restrict__ losses, unsigned k)
{
    const int slice = blockIdx.x;
    const int tid = threadIdx.x;
    const unsigned* hc = hist + slice * NBINS;

    __shared__ unsigned scnt[BLOCK];
    __shared__ float    ssum[BLOCK];
    __shared__ int      sbin;
    __shared__ unsigned skrem;

    const float binw = kRange / (float)NBINS;
    const int BPT = NBINS / BLOCK;   // 8 bins per thread, descending order

    unsigned cj[BPT];
    unsigned mycnt = 0;
#pragma unroll
    for (int j = 0; j < BPT; ++j) {
        cj[j] = hc[NBINS - 1 - (tid * BPT + j)];
        mycnt += cj[j];
    }
    scnt[tid] = mycnt;
    __syncthreads();

    unsigned P = 0;                        // exclusive prefix (naive, tiny)
    for (int u = 0; u < tid; ++u) P += scnt[u];

    if (P < k && P + mycnt >= k) {         // unique owner of the threshold bin
        unsigned cum = P;
#pragma unroll
        for (int j = 0; j < BPT; ++j) {
            if (cum + cj[j] >= k) {
                sbin = NBINS - 1 - (tid * BPT + j);
                skrem = k - cum;
                break;
            }
            cum += cj[j];
        }
    }
    __syncthreads();

    const int bstar = sbin;
    float mysum = 0.f;
#pragma unroll
    for (int j = 0; j < BPT; ++j) {
        int bin = NBINS - 1 - (tid * BPT + j);
        if (bin > bstar)
            mysum += (float)cj[j] * (((float)bin + 0.5f) * binw);
    }
    ssum[tid] = mysum;
    __syncthreads();
    for (int off = BLOCK / 2; off; off >>= 1) {
        if (tid < off) ssum[tid] += ssum[tid + off];
        __syncthreads();
    }

    if (tid == 0) {
        float total = ssum[0] + (float)skrem * (((float)bstar + 0.5f) * binw);
        float loss = total / (float)k;
        bool active = !((tmax[slice] == 0u) && (pmax[slice] == 0u));
        losses[slice] = active ? loss : 0.0f;
    }
}

__global__ void k_final(const float* __restrict__ losses, float* __restrict__ out)
{
    if (threadIdx.x == 0 && blockIdx.x == 0) {
        float total = 0.f;
        for (int b = 0; b < 4; ++b) {
            float s = 0.f;
            int cnt = 0;
            for (int c = 0; c < 4; ++c) {
                float l = losses[b * 4 + c];
                s += l;
                cnt += (l != 0.0f) ? 1 : 0;
            }
            total += s / (float)cnt;   // cnt==0 -> inf/nan, same as reference
        }
        out[0] = total / 4.0f;
    }
}

extern "C" void kernel_launch(void* const* d_in, const int* in_sizes, int n_in,
                              void* d_out, int out_size, void* d_ws, size_t ws_size,
                              hipStream_t stream) {
    const float* net = (const float*)d_in[0];
    const float* tgt = (const float*)d_in[1];
    const float* mp  = (const float*)d_in[2];
    float* out = (float*)d_out;

    const long long total = in_sizes[0];          // 33,554,432
    const long long V = total / NSLICE;           // 2,097,152
    const unsigned k = (unsigned)(V * 10 / 100);  // int(V*10/100) = 209,715

    char* ws = (char*)d_ws;
    unsigned* tmax   = (unsigned*)(ws + WS_TMAX);
    unsigned* pmax   = (unsigned*)(ws + WS_PMAX);
    float*    losses = (float*)(ws + WS_LOSS);
    unsigned* hist   = (unsigned*)(ws + WS_HIST);

    hipMemsetAsync(d_ws, 0, WS_USED, stream);

    k_hist<<<BPSH * NSLICE, BLOCK, 0, stream>>>(net, tgt, hist, tmax);
    k_pmax_cond<<<128 * NSLICE, BLOCK, 0, stream>>>(mp, tmax, pmax);
    k_select<<<NSLICE, BLOCK, 0, stream>>>(hist, tmax, pmax, losses, k);
    k_final<<<1, 64, 0, stream>>>(losses, out);
}